// Round 13
// baseline (342.546 us; speedup 1.0000x reference)
//
#include <hip/hip_runtime.h>
#include <hip/hip_bf16.h>
#include <stdint.h>

typedef __attribute__((ext_vector_type(8))) __bf16 bf16x8;
typedef __attribute__((ext_vector_type(4))) float f32x4;

__device__ __forceinline__ unsigned short f2bf(float f) {
  union { float f; unsigned u; } v; v.f = f;
  unsigned r = v.u + 0x7FFFu + ((v.u >> 16) & 1u);
  return (unsigned short)(r >> 16);
}

__device__ __forceinline__ float fast_exp2(float x) {
#if __has_builtin(__builtin_amdgcn_exp2f)
  return __builtin_amdgcn_exp2f(x);
#else
  return exp2f(x);
#endif
}

__device__ __forceinline__ void gload_lds16(const void* g, void* l) {
  __builtin_amdgcn_global_load_lds((const __attribute__((address_space(1))) void*)g,
                                   (__attribute__((address_space(3))) void*)l,
                                   16, 0, 0);
}

// ---------------- fused prep: x-cvt + rope table + 4 weight transposes ----------------
__global__ __launch_bounds__(256) void k_prep(
    const float* __restrict__ x, unsigned short* __restrict__ xb,
    const float* __restrict__ Wq, unsigned short* __restrict__ WqT,
    const float* __restrict__ Wdkv, unsigned short* __restrict__ WdkvT,
    const float* __restrict__ Wuk, unsigned short* __restrict__ WukT,
    const float* __restrict__ Wuv, unsigned short* __restrict__ WuvT,
    float* __restrict__ cosT, float* __restrict__ sinT) {
  const int bid = blockIdx.x;
  const int tid = threadIdx.x;
  if (bid < 8192) {  // x -> bf16
    int i = (bid * 256 + tid) * 4;
    float4 v = *reinterpret_cast<const float4*>(x + i);
    ushort4 o;
    o.x = f2bf(v.x); o.y = f2bf(v.y); o.z = f2bf(v.z); o.w = f2bf(v.w);
    *reinterpret_cast<ushort4*>(xb + i) = o;
    return;
  }
  if (bid >= 16384) {  // rope table
    int idx = (bid - 16384) * 256 + tid;
    int t = idx >> 6, j = idx & 63;
    float inv = powf(10000.f, -(float)j / 64.f);
    float ang = (float)t * inv;
    cosT[idx] = cosf(ang);
    sinT[idx] = sinf(ang);
    return;
  }
  // transpose+cvt: in (KxN f32) -> out (NxK bf16)
  const float* in; unsigned short* out; int K, N, lid;
  if (bid < 12288)      { in = Wq;   out = WqT;   K = 2048; N = 2048; lid = bid - 8192; }
  else if (bid < 14336) { in = Wdkv; out = WdkvT; K = 2048; N = 1024; lid = bid - 12288; }
  else if (bid < 15360) { in = Wuk;  out = WukT;  K = 512;  N = 2048; lid = bid - 14336; }
  else                  { in = Wuv;  out = WuvT;  K = 512;  N = 2048; lid = bid - 15360; }
  const int ntx = N >> 5;
  const int nt = lid % ntx, kt = lid / ntx;
  __shared__ float t[32][33];
  const int tx = tid & 31, ty = tid >> 5;
#pragma unroll
  for (int i = 0; i < 4; i++)
    t[ty + i * 8][tx] = in[(size_t)(kt * 32 + ty + i * 8) * N + nt * 32 + tx];
  __syncthreads();
#pragma unroll
  for (int i = 0; i < 4; i++)
    out[(size_t)(nt * 32 + ty + i * 8) * K + kt * 32 + tx] = f2bf(t[tx][ty + i * 8]);
}

// in: K x N fp32 row-major; out: N x K bf16 row-major — used for Wo only (wide dispatch)
__global__ __launch_bounds__(256) void k_transpose_cvt(const float* __restrict__ in,
                                                       unsigned short* __restrict__ out,
                                                       int K, int N) {
  __shared__ float t[32][33];
  int nt = blockIdx.x, kt = blockIdx.y;
  int tx = threadIdx.x, ty = threadIdx.y;  // 32 x 8
#pragma unroll
  for (int i = 0; i < 4; i++)
    t[ty + i * 8][tx] = in[(size_t)(kt * 32 + ty + i * 8) * N + nt * 32 + tx];
  __syncthreads();
#pragma unroll
  for (int i = 0; i < 4; i++)
    out[(size_t)(nt * 32 + ty + i * 8) * K + kt * 32 + tx] = f2bf(t[tx][ty + i * 8]);
}

// ---------------- GEMM: C = A(MxK) @ B (given as BT: NxK), bf16 in, f32 acc ----------------
// m97 2-barrier single-buffer structure. No XCD swizzle (R12 A/B: swizzle cost ~4us).
// No dbuf (R3), no k|v runtime-branch merge (R9).
template <int EPI>
__global__ __launch_bounds__(256, 2) void k_gemm(
    const unsigned short* __restrict__ A, int lda,
    const unsigned short* __restrict__ BT, int ldb,
    void* __restrict__ Cout, void* __restrict__ Cout2, int M, int N, int K,
    const float* __restrict__ cosT, const float* __restrict__ sinT) {
  __shared__ __attribute__((aligned(16))) unsigned short As[128 * 64];
  __shared__ __attribute__((aligned(16))) unsigned short Bs[128 * 64];
  const int tid = threadIdx.x;
  const int lane = tid & 63;
  const int w = tid >> 6;
  const int wr = w >> 1, wc = w & 1;
  const int m0 = blockIdx.y * 128, n0 = blockIdx.x * 128;

  f32x4 acc[4][4] = {};

  const int srow = w * 8 + (lane >> 3);
  const int sch = (lane & 7) * 8;
  const unsigned short* gA = A + (size_t)(m0 + srow) * lda + sch;
  const unsigned short* gB = BT + (size_t)(n0 + srow) * ldb + sch;
  unsigned short* lA = &As[srow * 64 + sch];
  unsigned short* lB = &Bs[srow * 64 + sch];

  for (int kt = 0; kt < K; kt += 64) {
    __syncthreads();
#pragma unroll
    for (int i = 0; i < 4; i++) {
      gload_lds16(gA + (size_t)(i * 32) * lda + kt, lA + i * 32 * 64);
      gload_lds16(gB + (size_t)(i * 32) * ldb + kt, lB + i * 32 * 64);
    }
    __syncthreads();
#pragma unroll
    for (int kk = 0; kk < 64; kk += 32) {
      bf16x8 af[4], bfr[4];
#pragma unroll
      for (int m = 0; m < 4; m++)
        af[m] = *reinterpret_cast<const bf16x8*>(&As[(wr * 64 + m * 16 + (lane & 15)) * 64 + kk + (lane >> 4) * 8]);
#pragma unroll
      for (int n = 0; n < 4; n++)
        bfr[n] = *reinterpret_cast<const bf16x8*>(&Bs[(wc * 64 + n * 16 + (lane & 15)) * 64 + kk + (lane >> 4) * 8]);
#pragma unroll
      for (int m = 0; m < 4; m++)
#pragma unroll
        for (int n = 0; n < 4; n++) {
          if (EPI == 3)
            acc[m][n] = __builtin_amdgcn_mfma_f32_16x16x32_bf16(bfr[n], af[m], acc[m][n], 0, 0, 0);
          else
            acc[m][n] = __builtin_amdgcn_mfma_f32_16x16x32_bf16(af[m], bfr[n], acc[m][n], 0, 0, 0);
        }
    }
  }

  const int rl = (lane >> 4) * 4;
  const int cl = lane & 15;
#pragma unroll
  for (int m = 0; m < 4; m++)
#pragma unroll
    for (int n = 0; n < 4; n++)
#pragma unroll
      for (int r = 0; r < 4; r++) {
        float v = acc[m][n][r];
        if (EPI == 4) {
          int gr = m0 + wr * 64 + m * 16 + rl + r;
          int gc = n0 + wc * 64 + n * 16 + cl;
          ((float*)Cout)[(size_t)gr * N + gc] = v;
        } else if (EPI == 1) {
          int gr = m0 + wr * 64 + m * 16 + rl + r;
          int gc = n0 + wc * 64 + n * 16 + cl;
          int b = gr >> 11, s = gr & 2047, h = gc >> 7, d = gc & 127;
          float p = __shfl_xor(v, 1);
          float c = cosT[s * 64 + (d & 63)];
          float sn = sinT[s * 64 + (d & 63)];
          v = v * c + ((d & 1) ? p : -p) * sn;
          ((unsigned short*)Cout)[((size_t)(b * 16 + h) * 2048 + s) * 128 + d] = f2bf(v);
        } else if (EPI == 5) {
          int gr = m0 + wr * 64 + m * 16 + rl + r;
          int gc = n0 + wc * 64 + n * 16 + cl;
          if (n0 < 2048) {  // wave-uniform branch: q-region with RoPE
            int b = gr >> 11, s = gr & 2047, h = gc >> 7, d = gc & 127;
            float p = __shfl_xor(v, 1);
            float c = cosT[s * 64 + (d & 63)];
            float sn = sinT[s * 64 + (d & 63)];
            v = v * c + ((d & 1) ? p : -p) * sn;
            ((unsigned short*)Cout)[((size_t)(b * 16 + h) * 2048 + s) * 128 + d] = f2bf(v);
          } else {  // dkv-region, row-major [4096][1024]
            ((unsigned short*)Cout2)[(size_t)gr * 1024 + (gc - 2048)] = f2bf(v);
          }
        } else {  // EPI == 3: acc holds C^T fragment
          int gd = n0 + wc * 64 + n * 16 + rl + r;   // N-dim (h*128+d)
          int gs = m0 + wr * 64 + m * 16 + cl;       // M-dim (b*2048+s)
          int b = gs >> 11, s = gs & 2047, h = gd >> 7, d = gd & 127;
          ((unsigned short*)Cout)[((size_t)(b * 16 + h) * 128 + d) * 2048 + s] = f2bf(v);
        }
      }
}

// ---------------- flash attention (no-max softmax, swapped-QK^T, KVBLK=32) ----------------
// Q,K: [32 heads][2048][128] bf16; Vt: [32][128][2048] bf16 (V^T); O: [4096][2048] bf16
// R13: KVBLK 64->32. LDS 80->40KB (Kdbuf16+Vdbuf16+P8) -> 4 blocks/CU (VGPR ~100 <= 128
// at bounds(256,4)) while KEEPING dbuf+prefetch ILP (R6: removing it serialized, 85->153).
// Doubles cross-block interleave of the serial QK^T->exp->PV chain (2-way was the 33%-util cap).
__global__ __launch_bounds__(256, 4) void k_attn(
    const unsigned short* __restrict__ Q,
    const unsigned short* __restrict__ Kt,
    const unsigned short* __restrict__ Vt,
    unsigned short* __restrict__ O) {
  __shared__ __attribute__((aligned(16))) unsigned short Kls[2][32 * 128];  // 16KB [s_k][d] swz
  __shared__ __attribute__((aligned(16))) unsigned short Vls[2][128 * 32];  // 16KB [d][s_k] swz
  __shared__ __attribute__((aligned(16))) unsigned short Pls[128 * 32];     //  8KB [q][s_k] swz
  // XCD-chunked bijective swizzle (nwg=512, 8 XCDs, 64 blocks/XCD -> 4 heads/XCD)
  const int flat = blockIdx.x + (blockIdx.y << 4);
  const int swz = (flat & 7) * 64 + (flat >> 3);
  const int qt = swz & 15, bh = swz >> 4;
  const int tid = threadIdx.x, lane = tid & 63, w = tid >> 6;
  const unsigned short* Qh = Q + (size_t)bh * 2048 * 128;
  const unsigned short* Kh = Kt + (size_t)bh * 2048 * 128;
  const unsigned short* Vh = Vt + (size_t)bh * 128 * 2048;
  const int q0 = qt * 128;

  bf16x8 qf[2][4];
#pragma unroll
  for (int m = 0; m < 2; m++)
#pragma unroll
    for (int kd = 0; kd < 4; kd++) {
      int row = q0 + w * 32 + m * 16 + (lane & 15);
      int k = kd * 32 + (lane >> 4) * 8;
      qf[m][kd] = *reinterpret_cast<const bf16x8*>(Qh + (size_t)row * 128 + k);
    }

  f32x4 accO[2][8] = {};
  float lsum[2] = {0.f, 0.f};  // row-sum for q = w*32 + m*16 + (lane&15)

  // flat-tid staging indices
  const int krr = tid >> 4;   // 16 K-rows/round (2 rounds)
  const int kc  = tid & 15;   // 16B chunk in 256B K-row
  const int vrr = tid >> 2;   // 64 V-rows/round (2 rounds)
  const int vc  = tid & 3;    // 16B chunk in 64B V-row

  auto stage = [&](int buf, int kt) {
#pragma unroll
    for (int i = 0; i < 2; i++) {  // K tile: 32 x 128, pre-swizzled global source
      int rr = krr + i * 16;
      gload_lds16(Kh + (size_t)(kt * 32 + rr) * 128 + ((kc ^ (rr & 7)) * 8),
                  (char*)Kls + buf * 8192 + rr * 256 + kc * 16);
    }
#pragma unroll
    for (int i = 0; i < 2; i++) {  // V^T tile: 128 x 32
      int rr = vrr + i * 64;
      gload_lds16(Vh + (size_t)rr * 2048 + kt * 32 + ((vc ^ (rr & 3)) * 8),
                  (char*)Vls + buf * 8192 + rr * 64 + vc * 16);
    }
  };

  stage(0, 0);
  __syncthreads();

  const float CL2 = 0.08838834764831845f * 1.44269504088896f;  // scale * log2(e)

  for (int kt = 0; kt < 64; kt++) {
    const int cur = kt & 1;
    if (kt + 1 < 64) stage(cur ^ 1, kt + 1);  // prefetch overlaps this tile's compute

    // S^T = K @ Q^T (swapped operands): C row = k (lane>>4)*4+r, col = q (lane&15)
    f32x4 accT[2][2] = {};
#pragma unroll
    for (int kd = 0; kd < 4; kd++) {
      bf16x8 kf[2];
#pragma unroll
      for (int n = 0; n < 2; n++) {
        int row = n * 16 + (lane & 15);
        int byte = cur * 8192 + row * 256 + (((kd * 32 + (lane >> 4) * 8) * 2) ^ ((row & 7) << 4));
        kf[n] = *reinterpret_cast<const bf16x8*>((const char*)Kls + byte);
      }
      __builtin_amdgcn_s_setprio(1);
#pragma unroll
      for (int n = 0; n < 2; n++)
#pragma unroll
        for (int m = 0; m < 2; m++)
          accT[n][m] = __builtin_amdgcn_mfma_f32_16x16x32_bf16(kf[n], qf[m][kd], accT[n][m], 0, 0, 0);
      __builtin_amdgcn_s_setprio(0);
    }

    // P = exp2(S*CL2); pack 4 consecutive k as 2x cvt_pk -> one b64 LDS write
#pragma unroll
    for (int n = 0; n < 2; n++)
#pragma unroll
      for (int m = 0; m < 2; m++) {
        float p0 = fast_exp2(accT[n][m][0] * CL2);
        float p1 = fast_exp2(accT[n][m][1] * CL2);
        float p2 = fast_exp2(accT[n][m][2] * CL2);
        float p3 = fast_exp2(accT[n][m][3] * CL2);
        lsum[m] += (p0 + p1) + (p2 + p3);
        unsigned pk0, pk1;
        asm("v_cvt_pk_bf16_f32 %0, %1, %2" : "=v"(pk0) : "v"(p0), "v"(p1));
        asm("v_cvt_pk_bf16_f32 %0, %1, %2" : "=v"(pk1) : "v"(p2), "v"(p3));
        int row = w * 32 + m * 16 + (lane & 15);
        int kcol2 = (n * 16 + (lane >> 4) * 4) * 2;  // byte offset in 64B row
        int byte = row * 64 + (kcol2 ^ ((row & 3) << 4));
        uint2 pk = {pk0, pk1};
        *reinterpret_cast<uint2*>((char*)Pls + byte) = pk;
      }

    // O += P @ V (single 32-wide K step)
    {
      bf16x8 pf[2], vf[8];
#pragma unroll
      for (int m = 0; m < 2; m++) {
        int row = w * 32 + m * 16 + (lane & 15);
        int byte = row * 64 + ((((lane >> 4) * 16)) ^ ((row & 3) << 4));
        pf[m] = *reinterpret_cast<const bf16x8*>((const char*)Pls + byte);
      }
#pragma unroll
      for (int n = 0; n < 8; n++) {
        int row = n * 16 + (lane & 15);
        int byte = cur * 8192 + row * 64 + ((((lane >> 4) * 16)) ^ ((row & 3) << 4));
        vf[n] = *reinterpret_cast<const bf16x8*>((const char*)Vls + byte);
      }
      __builtin_amdgcn_s_setprio(1);
#pragma unroll
      for (int m = 0; m < 2; m++)
#pragma unroll
        for (int n = 0; n < 8; n++)
          accO[m][n] = __builtin_amdgcn_mfma_f32_16x16x32_bf16(pf[m], vf[n], accO[m][n], 0, 0, 0);
      __builtin_amdgcn_s_setprio(0);
    }

    __syncthreads();  // drains prefetch (vmcnt) + syncs buffer reuse
  }

  // row-sum reduce across the 4 lane-groups, redistribute 1/l to C-fragment lanes.
  const int rl = (lane >> 4) * 4;
  float rv[2][4];
#pragma unroll
  for (int m = 0; m < 2; m++) {
    float s = lsum[m];
    s += __shfl_xor(s, 16);
    s += __shfl_xor(s, 32);
    float inv = 1.0f / s;
#pragma unroll
    for (int r = 0; r < 4; r++) rv[m][r] = __shfl(inv, rl + r);
  }

  const int b = bh >> 4, h = bh & 15;
#pragma unroll
  for (int m = 0; m < 2; m++)
#pragma unroll
    for (int n = 0; n < 8; n++)
#pragma unroll
      for (int r = 0; r < 4; r++) {
        int s = q0 + w * 32 + m * 16 + rl + r;
        int d = n * 16 + (lane & 15);
        O[((size_t)(b * 2048 + s)) * 2048 + h * 128 + d] = f2bf(accO[m][n][r] * rv[m][r]);
      }
}

// ---------------- launch ----------------

extern "C" void kernel_launch(void* const* d_in, const int* in_sizes, int n_in,
                              void* d_out, int out_size, void* d_ws, size_t ws_size,
                              hipStream_t stream) {
  const float* x    = (const float*)d_in[0];
  const float* Wq   = (const float*)d_in[1];
  const float* Wdkv = (const float*)d_in[2];
  const float* Wuk  = (const float*)d_in[3];
  const float* Wuv  = (const float*)d_in[4];
  const float* Wo   = (const float*)d_in[5];

  char* ws = (char*)d_ws;
  unsigned short* xb    = (unsigned short*)(ws + 0);          // 16MB; reused as attn-out
  unsigned short* WqT   = (unsigned short*)(ws + 16777216);   // 8MB; reused as WoT
  unsigned short* WdkvT = (unsigned short*)(ws + 25165824);   // 4MB (contiguous after WqT)
  unsigned short* WukT  = (unsigned short*)(ws + 29360128);   // 2MB
  unsigned short* WuvT  = (unsigned short*)(ws + 31457280);   // 2MB
  unsigned short* dkv   = (unsigned short*)(ws + 33554432);   // 8MB
  unsigned short* q_att = (unsigned short*)(ws + 41943040);   // 16MB
  unsigned short* k_att = (unsigned short*)(ws + 58720256);   // 16MB
  unsigned short* vT    = (unsigned short*)(ws + 75497472);   // 16MB
  float* cosT           = (float*)(ws + 92274688);            // 0.5MB
  float* sinT           = (float*)(ws + 92798976);            // 0.5MB

  // fused prep: x-cvt + Wq/Wdkv/Wuk/Wuv transposes + rope table (1 dispatch)
  k_prep<<<16896, 256, 0, stream>>>(x, xb, Wq, WqT, Wdkv, WdkvT, Wuk, WukT, Wuv, WuvT, cosT, sinT);

  // merged: [q | dkv] = x @ [Wq | Wdkv]  (N=3072; q gets RoPE+scatter, dkv row-major)
  k_gemm<5><<<dim3(24, 32), 256, 0, stream>>>(xb, 2048, WqT, 2048, q_att, dkv, 4096, 3072, 2048, cosT, sinT);
  // Wo^T into WqT slot (WqT dead after merged GEMM) — wide dispatch, ~8us
  k_transpose_cvt<<<dim3(64, 64), dim3(32, 8), 0, stream>>>(Wo, WqT, 2048, 2048);
  // k = dk@Wuk, +RoPE, -> [b][h][s][d]
  k_gemm<1><<<dim3(16, 32), 256, 0, stream>>>(dkv, 1024, WukT, 512, k_att, nullptr, 4096, 2048, 512, cosT, sinT);
  // v = dv@Wuv -> transposed [b][h][d][s]
  k_gemm<3><<<dim3(16, 32), 256, 0, stream>>>(dkv + 512, 1024, WuvT, 512, vT, nullptr, 4096, 2048, 512, nullptr, nullptr);
  // attention -> [4096][2048] bf16 (into xb slot, dead after merged GEMM)
  k_attn<<<dim3(16, 32), 256, 0, stream>>>(q_att, k_att, vT, xb);
  // out = ao @ Wo -> f32
  k_gemm<4><<<dim3(16, 32), 256, 0, stream>>>(xb, 2048, WqT, 2048, (float*)d_out, nullptr, 4096, 2048, 2048, nullptr, nullptr);
}

// Round 14
// 250.473 us; speedup vs baseline: 1.3676x; 1.3676x over previous
//
#include <hip/hip_runtime.h>
#include <hip/hip_bf16.h>
#include <stdint.h>

typedef __attribute__((ext_vector_type(8))) __bf16 bf16x8;
typedef __attribute__((ext_vector_type(4))) float f32x4;

__device__ __forceinline__ unsigned short f2bf(float f) {
  union { float f; unsigned u; } v; v.f = f;
  unsigned r = v.u + 0x7FFFu + ((v.u >> 16) & 1u);
  return (unsigned short)(r >> 16);
}

__device__ __forceinline__ float fast_exp2(float x) {
#if __has_builtin(__builtin_amdgcn_exp2f)
  return __builtin_amdgcn_exp2f(x);
#else
  return exp2f(x);
#endif
}

__device__ __forceinline__ void gload_lds16(const void* g, void* l) {
  __builtin_amdgcn_global_load_lds((const __attribute__((address_space(1))) void*)g,
                                   (__attribute__((address_space(3))) void*)l,
                                   16, 0, 0);
}

// ---------------- fused prep: x-cvt + rope table + 4 weight transposes ----------------
// R13 lesson catalog (attn): KVBLK=64 is load-bearing (32 degenerates swizzle + overhead ratio).
__global__ __launch_bounds__(256) void k_prep(
    const float* __restrict__ x, unsigned short* __restrict__ xb,
    const float* __restrict__ Wq, unsigned short* __restrict__ WqT,
    const float* __restrict__ Wdkv, unsigned short* __restrict__ WdkvT,
    const float* __restrict__ Wuk, unsigned short* __restrict__ WukT,
    const float* __restrict__ Wuv, unsigned short* __restrict__ WuvT,
    float* __restrict__ cosT, float* __restrict__ sinT) {
  const int bid = blockIdx.x;
  const int tid = threadIdx.x;
  if (bid < 8192) {  // x -> bf16
    int i = (bid * 256 + tid) * 4;
    float4 v = *reinterpret_cast<const float4*>(x + i);
    ushort4 o;
    o.x = f2bf(v.x); o.y = f2bf(v.y); o.z = f2bf(v.z); o.w = f2bf(v.w);
    *reinterpret_cast<ushort4*>(xb + i) = o;
    return;
  }
  if (bid >= 16384) {  // rope table
    int idx = (bid - 16384) * 256 + tid;
    int t = idx >> 6, j = idx & 63;
    float inv = powf(10000.f, -(float)j / 64.f);
    float ang = (float)t * inv;
    cosT[idx] = cosf(ang);
    sinT[idx] = sinf(ang);
    return;
  }
  // transpose+cvt: in (KxN f32) -> out (NxK bf16)
  const float* in; unsigned short* out; int K, N, lid;
  if (bid < 12288)      { in = Wq;   out = WqT;   K = 2048; N = 2048; lid = bid - 8192; }
  else if (bid < 14336) { in = Wdkv; out = WdkvT; K = 2048; N = 1024; lid = bid - 12288; }
  else if (bid < 15360) { in = Wuk;  out = WukT;  K = 512;  N = 2048; lid = bid - 14336; }
  else                  { in = Wuv;  out = WuvT;  K = 512;  N = 2048; lid = bid - 15360; }
  const int ntx = N >> 5;
  const int nt = lid % ntx, kt = lid / ntx;
  __shared__ float t[32][33];
  const int tx = tid & 31, ty = tid >> 5;
#pragma unroll
  for (int i = 0; i < 4; i++)
    t[ty + i * 8][tx] = in[(size_t)(kt * 32 + ty + i * 8) * N + nt * 32 + tx];
  __syncthreads();
#pragma unroll
  for (int i = 0; i < 4; i++)
    out[(size_t)(nt * 32 + ty + i * 8) * K + kt * 32 + tx] = f2bf(t[tx][ty + i * 8]);
}

// in: K x N fp32 row-major; out: N x K bf16 row-major — used for Wo only (wide dispatch)
__global__ __launch_bounds__(256) void k_transpose_cvt(const float* __restrict__ in,
                                                       unsigned short* __restrict__ out,
                                                       int K, int N) {
  __shared__ float t[32][33];
  int nt = blockIdx.x, kt = blockIdx.y;
  int tx = threadIdx.x, ty = threadIdx.y;  // 32 x 8
#pragma unroll
  for (int i = 0; i < 4; i++)
    t[ty + i * 8][tx] = in[(size_t)(kt * 32 + ty + i * 8) * N + nt * 32 + tx];
  __syncthreads();
#pragma unroll
  for (int i = 0; i < 4; i++)
    out[(size_t)(nt * 32 + ty + i * 8) * K + kt * 32 + tx] = f2bf(t[tx][ty + i * 8]);
}

// ---------------- GEMM: C = A(MxK) @ B (given as BT: NxK), bf16 in, f32 acc ----------------
// m97 2-barrier single-buffer structure (~874 TF). No XCD swizzle (R12: −4us), no dbuf (R3),
// no k|v runtime-branch merge (R9), no serial-tail fusion (R11).
template <int EPI>
__global__ __launch_bounds__(256, 2) void k_gemm(
    const unsigned short* __restrict__ A, int lda,
    const unsigned short* __restrict__ BT, int ldb,
    void* __restrict__ Cout, void* __restrict__ Cout2, int M, int N, int K,
    const float* __restrict__ cosT, const float* __restrict__ sinT) {
  __shared__ __attribute__((aligned(16))) unsigned short As[128 * 64];
  __shared__ __attribute__((aligned(16))) unsigned short Bs[128 * 64];
  const int tid = threadIdx.x;
  const int lane = tid & 63;
  const int w = tid >> 6;
  const int wr = w >> 1, wc = w & 1;
  const int m0 = blockIdx.y * 128, n0 = blockIdx.x * 128;

  f32x4 acc[4][4] = {};

  const int srow = w * 8 + (lane >> 3);
  const int sch = (lane & 7) * 8;
  const unsigned short* gA = A + (size_t)(m0 + srow) * lda + sch;
  const unsigned short* gB = BT + (size_t)(n0 + srow) * ldb + sch;
  unsigned short* lA = &As[srow * 64 + sch];
  unsigned short* lB = &Bs[srow * 64 + sch];

  for (int kt = 0; kt < K; kt += 64) {
    __syncthreads();
#pragma unroll
    for (int i = 0; i < 4; i++) {
      gload_lds16(gA + (size_t)(i * 32) * lda + kt, lA + i * 32 * 64);
      gload_lds16(gB + (size_t)(i * 32) * ldb + kt, lB + i * 32 * 64);
    }
    __syncthreads();
#pragma unroll
    for (int kk = 0; kk < 64; kk += 32) {
      bf16x8 af[4], bfr[4];
#pragma unroll
      for (int m = 0; m < 4; m++)
        af[m] = *reinterpret_cast<const bf16x8*>(&As[(wr * 64 + m * 16 + (lane & 15)) * 64 + kk + (lane >> 4) * 8]);
#pragma unroll
      for (int n = 0; n < 4; n++)
        bfr[n] = *reinterpret_cast<const bf16x8*>(&Bs[(wc * 64 + n * 16 + (lane & 15)) * 64 + kk + (lane >> 4) * 8]);
#pragma unroll
      for (int m = 0; m < 4; m++)
#pragma unroll
        for (int n = 0; n < 4; n++) {
          if (EPI == 3)
            acc[m][n] = __builtin_amdgcn_mfma_f32_16x16x32_bf16(bfr[n], af[m], acc[m][n], 0, 0, 0);
          else
            acc[m][n] = __builtin_amdgcn_mfma_f32_16x16x32_bf16(af[m], bfr[n], acc[m][n], 0, 0, 0);
        }
    }
  }

  const int rl = (lane >> 4) * 4;
  const int cl = lane & 15;
#pragma unroll
  for (int m = 0; m < 4; m++)
#pragma unroll
    for (int n = 0; n < 4; n++)
#pragma unroll
      for (int r = 0; r < 4; r++) {
        float v = acc[m][n][r];
        if (EPI == 4) {
          int gr = m0 + wr * 64 + m * 16 + rl + r;
          int gc = n0 + wc * 64 + n * 16 + cl;
          ((float*)Cout)[(size_t)gr * N + gc] = v;
        } else if (EPI == 1) {
          int gr = m0 + wr * 64 + m * 16 + rl + r;
          int gc = n0 + wc * 64 + n * 16 + cl;
          int b = gr >> 11, s = gr & 2047, h = gc >> 7, d = gc & 127;
          float p = __shfl_xor(v, 1);
          float c = cosT[s * 64 + (d & 63)];
          float sn = sinT[s * 64 + (d & 63)];
          v = v * c + ((d & 1) ? p : -p) * sn;
          ((unsigned short*)Cout)[((size_t)(b * 16 + h) * 2048 + s) * 128 + d] = f2bf(v);
        } else if (EPI == 5) {
          int gr = m0 + wr * 64 + m * 16 + rl + r;
          int gc = n0 + wc * 64 + n * 16 + cl;
          if (n0 < 2048) {  // wave-uniform branch: q-region with RoPE
            int b = gr >> 11, s = gr & 2047, h = gc >> 7, d = gc & 127;
            float p = __shfl_xor(v, 1);
            float c = cosT[s * 64 + (d & 63)];
            float sn = sinT[s * 64 + (d & 63)];
            v = v * c + ((d & 1) ? p : -p) * sn;
            ((unsigned short*)Cout)[((size_t)(b * 16 + h) * 2048 + s) * 128 + d] = f2bf(v);
          } else {  // dkv-region, row-major [4096][1024]
            ((unsigned short*)Cout2)[(size_t)gr * 1024 + (gc - 2048)] = f2bf(v);
          }
        } else {  // EPI == 3: acc holds C^T fragment
          int gd = n0 + wc * 64 + n * 16 + rl + r;   // N-dim (h*128+d)
          int gs = m0 + wr * 64 + m * 16 + cl;       // M-dim (b*2048+s)
          int b = gs >> 11, s = gs & 2047, h = gd >> 7, d = gd & 127;
          ((unsigned short*)Cout)[((size_t)(b * 16 + h) * 128 + d) * 2048 + s] = f2bf(v);
        }
      }
}

// ---------------- flash attention (no-max softmax, swapped-QK^T P-pack) ----------------
// Q,K: [32 heads][2048][128] bf16; Vt: [32][128][2048] bf16 (V^T); O: [4096][2048] bf16
// R7/R10-proven structure (83.5us = 823 TF eff, 33% MfmaUtil — at this structure's ladder
// level). KVBLK=64 load-bearing (R13: 32 degenerates swizzle, 2.2x regress). V in LDS
// (R8: global-V spills to scratch). dbuf+prefetch ILP required (R6: single-buf 1.8x regress).
__global__ __launch_bounds__(256, 2) void k_attn(
    const unsigned short* __restrict__ Q,
    const unsigned short* __restrict__ Kt,
    const unsigned short* __restrict__ Vt,
    unsigned short* __restrict__ O) {
  __shared__ __attribute__((aligned(16))) unsigned short Kls[2][64 * 128];  // [s_k][d], swizzled
  __shared__ __attribute__((aligned(16))) unsigned short Vls[2][128 * 64];  // [d][s_k], swizzled
  __shared__ __attribute__((aligned(16))) unsigned short Pls[128 * 64];     // [q][s_k], swizzled
  // XCD-chunked bijective swizzle (nwg=512, 8 XCDs, 64 blocks/XCD -> 4 heads/XCD)
  const int flat = blockIdx.x + (blockIdx.y << 4);
  const int swz = (flat & 7) * 64 + (flat >> 3);
  const int qt = swz & 15, bh = swz >> 4;
  const int tid = threadIdx.x, lane = tid & 63, w = tid >> 6;
  const unsigned short* Qh = Q + (size_t)bh * 2048 * 128;
  const unsigned short* Kh = Kt + (size_t)bh * 2048 * 128;
  const unsigned short* Vh = Vt + (size_t)bh * 128 * 2048;
  const int q0 = qt * 128;

  bf16x8 qf[2][4];
#pragma unroll
  for (int m = 0; m < 2; m++)
#pragma unroll
    for (int kd = 0; kd < 4; kd++) {
      int row = q0 + w * 32 + m * 16 + (lane & 15);
      int k = kd * 32 + (lane >> 4) * 8;
      qf[m][kd] = *reinterpret_cast<const bf16x8*>(Qh + (size_t)row * 128 + k);
    }

  f32x4 accO[2][8] = {};
  float lsum[2] = {0.f, 0.f};  // row-sum for q = w*32 + m*16 + (lane&15)

  const int kr0 = w * 4 + (lane >> 4);
  const int kcb = lane & 15;
  const int vr0 = w * 8 + (lane >> 3);
  const int vcb = lane & 7;

  auto stage = [&](int buf, int kt) {
#pragma unroll
    for (int i = 0; i < 4; i++) {  // K tile: 64 x 128, pre-swizzled global source
      int rr = kr0 + i * 16;
      gload_lds16(Kh + (size_t)(kt * 64 + rr) * 128 + ((kcb ^ (rr & 7)) * 8),
                  (char*)Kls + buf * 16384 + rr * 256 + kcb * 16);
    }
#pragma unroll
    for (int i = 0; i < 4; i++) {  // V^T tile: 128 x 64
      int rr = vr0 + i * 32;
      gload_lds16(Vh + (size_t)rr * 2048 + kt * 64 + ((vcb ^ (rr & 7)) * 8),
                  (char*)Vls + buf * 16384 + rr * 128 + vcb * 16);
    }
  };

  stage(0, 0);
  __syncthreads();

  const float CL2 = 0.08838834764831845f * 1.44269504088896f;  // scale * log2(e)

  for (int kt = 0; kt < 32; kt++) {
    const int cur = kt & 1;
    if (kt + 1 < 32) stage(cur ^ 1, kt + 1);  // prefetch overlaps this tile's compute

    // S^T = K @ Q^T (swapped operands): C row = k (lane>>4)*4+r, col = q (lane&15)
    f32x4 accT[4][2] = {};
#pragma unroll
    for (int kd = 0; kd < 4; kd++) {
      bf16x8 kf[4];
#pragma unroll
      for (int n = 0; n < 4; n++) {
        int row = n * 16 + (lane & 15);
        int byte = cur * 16384 + row * 256 + (((kd * 32 + (lane >> 4) * 8) * 2) ^ ((row & 7) << 4));
        kf[n] = *reinterpret_cast<const bf16x8*>((const char*)Kls + byte);
      }
      __builtin_amdgcn_s_setprio(1);
#pragma unroll
      for (int n = 0; n < 4; n++)
#pragma unroll
        for (int m = 0; m < 2; m++)
          accT[n][m] = __builtin_amdgcn_mfma_f32_16x16x32_bf16(kf[n], qf[m][kd], accT[n][m], 0, 0, 0);
      __builtin_amdgcn_s_setprio(0);
    }

    // P = exp2(S*CL2); pack 4 consecutive k as 2x cvt_pk -> one b64 LDS write
#pragma unroll
    for (int n = 0; n < 4; n++)
#pragma unroll
      for (int m = 0; m < 2; m++) {
        float p0 = fast_exp2(accT[n][m][0] * CL2);
        float p1 = fast_exp2(accT[n][m][1] * CL2);
        float p2 = fast_exp2(accT[n][m][2] * CL2);
        float p3 = fast_exp2(accT[n][m][3] * CL2);
        lsum[m] += (p0 + p1) + (p2 + p3);
        unsigned pk0, pk1;
        asm("v_cvt_pk_bf16_f32 %0, %1, %2" : "=v"(pk0) : "v"(p0), "v"(p1));
        asm("v_cvt_pk_bf16_f32 %0, %1, %2" : "=v"(pk1) : "v"(p2), "v"(p3));
        int row = w * 32 + m * 16 + (lane & 15);
        int kcol = n * 16 + (lane >> 4) * 4;
        int byte = row * 128 + ((kcol * 2) ^ ((row & 7) << 4));
        uint2 pk = {pk0, pk1};
        *reinterpret_cast<uint2*>((char*)Pls + byte) = pk;
      }

    // O += P @ V (unchanged read path)
#pragma unroll
    for (int kk = 0; kk < 2; kk++) {
      bf16x8 pf[2], vf[8];
#pragma unroll
      for (int m = 0; m < 2; m++) {
        int row = w * 32 + m * 16 + (lane & 15);
        int byte = row * 128 + (((kk * 32 + (lane >> 4) * 8) * 2) ^ ((row & 7) << 4));
        pf[m] = *reinterpret_cast<const bf16x8*>((const char*)Pls + byte);
      }
#pragma unroll
      for (int n = 0; n < 8; n++) {
        int row = n * 16 + (lane & 15);
        int byte = cur * 16384 + row * 128 + (((kk * 32 + (lane >> 4) * 8) * 2) ^ ((row & 7) << 4));
        vf[n] = *reinterpret_cast<const bf16x8*>((const char*)Vls + byte);
      }
      __builtin_amdgcn_s_setprio(1);
#pragma unroll
      for (int m = 0; m < 2; m++)
#pragma unroll
        for (int n = 0; n < 8; n++)
          accO[m][n] = __builtin_amdgcn_mfma_f32_16x16x32_bf16(pf[m], vf[n], accO[m][n], 0, 0, 0);
      __builtin_amdgcn_s_setprio(0);
    }

    __syncthreads();  // drains prefetch (vmcnt) + syncs buffer reuse
  }

  // row-sum reduce across the 4 lane-groups, redistribute 1/l to C-fragment lanes.
  const int rl = (lane >> 4) * 4;
  float rv[2][4];
#pragma unroll
  for (int m = 0; m < 2; m++) {
    float s = lsum[m];
    s += __shfl_xor(s, 16);
    s += __shfl_xor(s, 32);
    float inv = 1.0f / s;
#pragma unroll
    for (int r = 0; r < 4; r++) rv[m][r] = __shfl(inv, rl + r);
  }

  const int b = bh >> 4, h = bh & 15;
#pragma unroll
  for (int m = 0; m < 2; m++)
#pragma unroll
    for (int n = 0; n < 8; n++)
#pragma unroll
      for (int r = 0; r < 4; r++) {
        int s = q0 + w * 32 + m * 16 + rl + r;
        int d = n * 16 + (lane & 15);
        O[((size_t)(b * 2048 + s)) * 2048 + h * 128 + d] = f2bf(accO[m][n][r] * rv[m][r]);
      }
}

// ---------------- launch ----------------

extern "C" void kernel_launch(void* const* d_in, const int* in_sizes, int n_in,
                              void* d_out, int out_size, void* d_ws, size_t ws_size,
                              hipStream_t stream) {
  const float* x    = (const float*)d_in[0];
  const float* Wq   = (const float*)d_in[1];
  const float* Wdkv = (const float*)d_in[2];
  const float* Wuk  = (const float*)d_in[3];
  const float* Wuv  = (const float*)d_in[4];
  const float* Wo   = (const float*)d_in[5];

  char* ws = (char*)d_ws;
  unsigned short* xb    = (unsigned short*)(ws + 0);          // 16MB; reused as attn-out
  unsigned short* WqT   = (unsigned short*)(ws + 16777216);   // 8MB; reused as WoT
  unsigned short* WdkvT = (unsigned short*)(ws + 25165824);   // 4MB (contiguous after WqT)
  unsigned short* WukT  = (unsigned short*)(ws + 29360128);   // 2MB
  unsigned short* WuvT  = (unsigned short*)(ws + 31457280);   // 2MB
  unsigned short* dkv   = (unsigned short*)(ws + 33554432);   // 8MB
  unsigned short* q_att = (unsigned short*)(ws + 41943040);   // 16MB
  unsigned short* k_att = (unsigned short*)(ws + 58720256);   // 16MB
  unsigned short* vT    = (unsigned short*)(ws + 75497472);   // 16MB
  float* cosT           = (float*)(ws + 92274688);            // 0.5MB
  float* sinT           = (float*)(ws + 92798976);            // 0.5MB

  // fused prep: x-cvt + Wq/Wdkv/Wuk/Wuv transposes + rope table (1 dispatch)
  k_prep<<<16896, 256, 0, stream>>>(x, xb, Wq, WqT, Wdkv, WdkvT, Wuk, WukT, Wuv, WuvT, cosT, sinT);

  // merged: [q | dkv] = x @ [Wq | Wdkv]  (N=3072; q gets RoPE+scatter, dkv row-major)
  k_gemm<5><<<dim3(24, 32), 256, 0, stream>>>(xb, 2048, WqT, 2048, q_att, dkv, 4096, 3072, 2048, cosT, sinT);
  // Wo^T into WqT slot (WqT dead after merged GEMM) — wide dispatch, ~8us
  k_transpose_cvt<<<dim3(64, 64), dim3(32, 8), 0, stream>>>(Wo, WqT, 2048, 2048);
  // k = dk@Wuk, +RoPE, -> [b][h][s][d]
  k_gemm<1><<<dim3(16, 32), 256, 0, stream>>>(dkv, 1024, WukT, 512, k_att, nullptr, 4096, 2048, 512, cosT, sinT);
  // v = dv@Wuv -> transposed [b][h][d][s]
  k_gemm<3><<<dim3(16, 32), 256, 0, stream>>>(dkv + 512, 1024, WuvT, 512, vT, nullptr, 4096, 2048, 512, nullptr, nullptr);
  // attention -> [4096][2048] bf16 (into xb slot, dead after merged GEMM)
  k_attn<<<dim3(16, 32), 256, 0, stream>>>(q_att, k_att, vT, xb);
  // out = ao @ Wo -> f32
  k_gemm<4><<<dim3(16, 32), 256, 0, stream>>>(xb, 2048, WqT, 2048, (float*)d_out, nullptr, 4096, 2048, 2048, nullptr, nullptr);
}

// Round 15
// 247.810 us; speedup vs baseline: 1.3823x; 1.0107x over previous
//
#include <hip/hip_runtime.h>
#include <hip/hip_bf16.h>
#include <stdint.h>

typedef __attribute__((ext_vector_type(8))) __bf16 bf16x8;
typedef __attribute__((ext_vector_type(4))) float f32x4;

__device__ __forceinline__ unsigned short f2bf(float f) {
  union { float f; unsigned u; } v; v.f = f;
  unsigned r = v.u + 0x7FFFu + ((v.u >> 16) & 1u);
  return (unsigned short)(r >> 16);
}

__device__ __forceinline__ float fast_exp2(float x) {
#if __has_builtin(__builtin_amdgcn_exp2f)
  return __builtin_amdgcn_exp2f(x);
#else
  return exp2f(x);
#endif
}

__device__ __forceinline__ void gload_lds16(const void* g, void* l) {
  __builtin_amdgcn_global_load_lds((const __attribute__((address_space(1))) void*)g,
                                   (__attribute__((address_space(3))) void*)l,
                                   16, 0, 0);
}

// ---------------- fused prep: x-cvt + rope table + 4 weight transposes ----------------
__global__ __launch_bounds__(256) void k_prep(
    const float* __restrict__ x, unsigned short* __restrict__ xb,
    const float* __restrict__ Wq, unsigned short* __restrict__ WqT,
    const float* __restrict__ Wdkv, unsigned short* __restrict__ WdkvT,
    const float* __restrict__ Wuk, unsigned short* __restrict__ WukT,
    const float* __restrict__ Wuv, unsigned short* __restrict__ WuvT,
    float* __restrict__ cosT, float* __restrict__ sinT) {
  const int bid = blockIdx.x;
  const int tid = threadIdx.x;
  if (bid < 8192) {  // x -> bf16
    int i = (bid * 256 + tid) * 4;
    float4 v = *reinterpret_cast<const float4*>(x + i);
    ushort4 o;
    o.x = f2bf(v.x); o.y = f2bf(v.y); o.z = f2bf(v.z); o.w = f2bf(v.w);
    *reinterpret_cast<ushort4*>(xb + i) = o;
    return;
  }
  if (bid >= 16384) {  // rope table
    int idx = (bid - 16384) * 256 + tid;
    int t = idx >> 6, j = idx & 63;
    float inv = powf(10000.f, -(float)j / 64.f);
    float ang = (float)t * inv;
    cosT[idx] = cosf(ang);
    sinT[idx] = sinf(ang);
    return;
  }
  // transpose+cvt: in (KxN f32) -> out (NxK bf16)
  const float* in; unsigned short* out; int K, N, lid;
  if (bid < 12288)      { in = Wq;   out = WqT;   K = 2048; N = 2048; lid = bid - 8192; }
  else if (bid < 14336) { in = Wdkv; out = WdkvT; K = 2048; N = 1024; lid = bid - 12288; }
  else if (bid < 15360) { in = Wuk;  out = WukT;  K = 512;  N = 2048; lid = bid - 14336; }
  else                  { in = Wuv;  out = WuvT;  K = 512;  N = 2048; lid = bid - 15360; }
  const int ntx = N >> 5;
  const int nt = lid % ntx, kt = lid / ntx;
  __shared__ float t[32][33];
  const int tx = tid & 31, ty = tid >> 5;
#pragma unroll
  for (int i = 0; i < 4; i++)
    t[ty + i * 8][tx] = in[(size_t)(kt * 32 + ty + i * 8) * N + nt * 32 + tx];
  __syncthreads();
#pragma unroll
  for (int i = 0; i < 4; i++)
    out[(size_t)(nt * 32 + ty + i * 8) * K + kt * 32 + tx] = f2bf(t[tx][ty + i * 8]);
}

// ---------------- GEMM: C = A(MxK) @ B (given as BT: NxK), bf16 in, f32 acc ----------------
// m97 2-barrier single-buffer structure (~874 TF). No XCD swizzle (R12: −4us), no dbuf (R3),
// no serial-tail fusion (R11: 32 blocks x 128 serial tiles = 115us dispatch).
// EPI: 1 = RoPE + [b][h][s][d]; 4 = f32 row-major; 5 = merged q|dkv;
//      6 = merged k|v|WoT, 1D grid 2048, SINGLE non-swapped inner loop (R9 lesson:
//          runtime operand-swap branch in K-loop cost +23us — avoided via vT = WuvT @ dv^T
//          reformulation, so both halves share identical MFMA orientation):
//            bid<512:       k = dk@Wuk +RoPE -> Cout (A=dkv lda=1024, BT=WukT ldb=512)
//            512<=bid<1024: vT = WuvT@dv^T   -> Cout2 (A=X1=WuvT lda=512, BT=dkv+512 ldb=1024)
//            bid>=1024:     Wo transpose, 1024 wide blocks x 4 bounded tiles (X2=Wo, X3=WoT)
template <int EPI>
__global__ __launch_bounds__(256, 2) void k_gemm(
    const unsigned short* __restrict__ A, int lda,
    const unsigned short* __restrict__ BT, int ldb,
    void* __restrict__ Cout, void* __restrict__ Cout2, int M, int N, int K,
    const float* __restrict__ cosT, const float* __restrict__ sinT,
    const unsigned short* __restrict__ X1, const float* __restrict__ X2,
    unsigned short* __restrict__ X3) {
  __shared__ __attribute__((aligned(16))) unsigned short As[128 * 64];
  __shared__ __attribute__((aligned(16))) unsigned short Bs[128 * 64];
  const int tid = threadIdx.x;

  if (EPI == 6 && blockIdx.x >= 1024) {
    // folded Wo transpose: 1024 blocks x 4 tiles of 32x32 (f32 2048x2048 -> bf16 T)
    float (*t)[33] = (float(*)[33])As;  // overlay, LDS size unchanged
    const int tx = tid & 31, ty = tid >> 5;
#pragma unroll
    for (int it = 0; it < 4; ++it) {
      int tile = (blockIdx.x - 1024) * 4 + it;
      int nt = tile & 63, kt2 = tile >> 6;
#pragma unroll
      for (int i = 0; i < 4; i++)
        t[ty + i * 8][tx] = X2[(size_t)(kt2 * 32 + ty + i * 8) * 2048 + nt * 32 + tx];
      __syncthreads();
#pragma unroll
      for (int i = 0; i < 4; i++)
        X3[(size_t)(nt * 32 + ty + i * 8) * 2048 + kt2 * 32 + tx] = f2bf(t[tx][ty + i * 8]);
      __syncthreads();
    }
    return;
  }

  const int lane = tid & 63;
  const int w = tid >> 6;
  const int wr = w >> 1, wc = w & 1;

  // per-block-uniform operand/tile selection (before the K-loop; inner loop is shared)
  const unsigned short* Ap = A; int ldA = lda;
  const unsigned short* Bp = BT; int ldB = ldb;
  int m0, n0; bool vmode = false;
  if (EPI == 6) {
    const int bid = blockIdx.x;
    if (bid < 512) { m0 = (bid >> 4) * 128; n0 = (bid & 15) * 128; }
    else {
      vmode = true;
      Ap = X1; ldA = 512; Bp = A + 512; ldB = 1024;
      const int b2 = bid - 512;
      m0 = (b2 & 15) * 128; n0 = (b2 >> 4) * 128;
    }
  } else {
    m0 = blockIdx.y * 128; n0 = blockIdx.x * 128;
  }

  f32x4 acc[4][4] = {};

  const int srow = w * 8 + (lane >> 3);
  const int sch = (lane & 7) * 8;
  const unsigned short* gA = Ap + (size_t)(m0 + srow) * ldA + sch;
  const unsigned short* gB = Bp + (size_t)(n0 + srow) * ldB + sch;
  unsigned short* lA = &As[srow * 64 + sch];
  unsigned short* lB = &Bs[srow * 64 + sch];

  for (int kt = 0; kt < K; kt += 64) {
    __syncthreads();
#pragma unroll
    for (int i = 0; i < 4; i++) {
      gload_lds16(gA + (size_t)(i * 32) * ldA + kt, lA + i * 32 * 64);
      gload_lds16(gB + (size_t)(i * 32) * ldB + kt, lB + i * 32 * 64);
    }
    __syncthreads();
#pragma unroll
    for (int kk = 0; kk < 64; kk += 32) {
      bf16x8 af[4], bfr[4];
#pragma unroll
      for (int m = 0; m < 4; m++)
        af[m] = *reinterpret_cast<const bf16x8*>(&As[(wr * 64 + m * 16 + (lane & 15)) * 64 + kk + (lane >> 4) * 8]);
#pragma unroll
      for (int n = 0; n < 4; n++)
        bfr[n] = *reinterpret_cast<const bf16x8*>(&Bs[(wc * 64 + n * 16 + (lane & 15)) * 64 + kk + (lane >> 4) * 8]);
#pragma unroll
      for (int m = 0; m < 4; m++)
#pragma unroll
        for (int n = 0; n < 4; n++)
          acc[m][n] = __builtin_amdgcn_mfma_f32_16x16x32_bf16(af[m], bfr[n], acc[m][n], 0, 0, 0);
    }
  }

  const int rl = (lane >> 4) * 4;
  const int cl = lane & 15;
#pragma unroll
  for (int m = 0; m < 4; m++)
#pragma unroll
    for (int n = 0; n < 4; n++)
#pragma unroll
      for (int r = 0; r < 4; r++) {
        float v = acc[m][n][r];
        int gr = m0 + wr * 64 + m * 16 + rl + r;
        int gc = n0 + wc * 64 + n * 16 + cl;
        if (EPI == 4) {
          ((float*)Cout)[(size_t)gr * N + gc] = v;
        } else if (EPI == 1) {
          int b = gr >> 11, s = gr & 2047, h = gc >> 7, d = gc & 127;
          float p = __shfl_xor(v, 1);
          float c = cosT[s * 64 + (d & 63)];
          float sn = sinT[s * 64 + (d & 63)];
          v = v * c + ((d & 1) ? p : -p) * sn;
          ((unsigned short*)Cout)[((size_t)(b * 16 + h) * 2048 + s) * 128 + d] = f2bf(v);
        } else if (EPI == 5) {
          if (n0 < 2048) {  // q-region with RoPE (wave-uniform)
            int b = gr >> 11, s = gr & 2047, h = gc >> 7, d = gc & 127;
            float p = __shfl_xor(v, 1);
            float c = cosT[s * 64 + (d & 63)];
            float sn = sinT[s * 64 + (d & 63)];
            v = v * c + ((d & 1) ? p : -p) * sn;
            ((unsigned short*)Cout)[((size_t)(b * 16 + h) * 2048 + s) * 128 + d] = f2bf(v);
          } else {  // dkv-region, row-major [4096][1024]
            ((unsigned short*)Cout2)[(size_t)gr * 1024 + (gc - 2048)] = f2bf(v);
          }
        } else {  // EPI == 6
          if (!vmode) {  // k: RoPE + [b][h][s][d]
            int b = gr >> 11, s = gr & 2047, h = gc >> 7, d = gc & 127;
            float p = __shfl_xor(v, 1);
            float c = cosT[s * 64 + (d & 63)];
            float sn = sinT[s * 64 + (d & 63)];
            v = v * c + ((d & 1) ? p : -p) * sn;
            ((unsigned short*)Cout)[((size_t)(b * 16 + h) * 2048 + s) * 128 + d] = f2bf(v);
          } else {  // vT: C'[h*128+d][b*2048+s] -> [b][h][d][s]
            int h = gr >> 7, d = gr & 127, b = gc >> 11, s = gc & 2047;
            ((unsigned short*)Cout2)[(((size_t)(b * 16 + h) * 128) + d) * 2048 + s] = f2bf(v);
          }
        }
      }
}

// ---------------- flash attention (no-max softmax, swapped-QK^T P-pack) ----------------
// R7/R10-proven structure (83.5us = 823 TF eff). KVBLK=64 load-bearing (R13). V in LDS (R8).
// dbuf+prefetch ILP required (R6). Register-floored at 2 blocks/CU.
__global__ __launch_bounds__(256, 2) void k_attn(
    const unsigned short* __restrict__ Q,
    const unsigned short* __restrict__ Kt,
    const unsigned short* __restrict__ Vt,
    unsigned short* __restrict__ O) {
  __shared__ __attribute__((aligned(16))) unsigned short Kls[2][64 * 128];  // [s_k][d], swizzled
  __shared__ __attribute__((aligned(16))) unsigned short Vls[2][128 * 64];  // [d][s_k], swizzled
  __shared__ __attribute__((aligned(16))) unsigned short Pls[128 * 64];     // [q][s_k], swizzled
  // XCD-chunked bijective swizzle (nwg=512, 8 XCDs, 64 blocks/XCD -> 4 heads/XCD)
  const int flat = blockIdx.x + (blockIdx.y << 4);
  const int swz = (flat & 7) * 64 + (flat >> 3);
  const int qt = swz & 15, bh = swz >> 4;
  const int tid = threadIdx.x, lane = tid & 63, w = tid >> 6;
  const unsigned short* Qh = Q + (size_t)bh * 2048 * 128;
  const unsigned short* Kh = Kt + (size_t)bh * 2048 * 128;
  const unsigned short* Vh = Vt + (size_t)bh * 128 * 2048;
  const int q0 = qt * 128;

  bf16x8 qf[2][4];
#pragma unroll
  for (int m = 0; m < 2; m++)
#pragma unroll
    for (int kd = 0; kd < 4; kd++) {
      int row = q0 + w * 32 + m * 16 + (lane & 15);
      int k = kd * 32 + (lane >> 4) * 8;
      qf[m][kd] = *reinterpret_cast<const bf16x8*>(Qh + (size_t)row * 128 + k);
    }

  f32x4 accO[2][8] = {};
  float lsum[2] = {0.f, 0.f};  // row-sum for q = w*32 + m*16 + (lane&15)

  const int kr0 = w * 4 + (lane >> 4);
  const int kcb = lane & 15;
  const int vr0 = w * 8 + (lane >> 3);
  const int vcb = lane & 7;

  auto stage = [&](int buf, int kt) {
#pragma unroll
    for (int i = 0; i < 4; i++) {  // K tile: 64 x 128, pre-swizzled global source
      int rr = kr0 + i * 16;
      gload_lds16(Kh + (size_t)(kt * 64 + rr) * 128 + ((kcb ^ (rr & 7)) * 8),
                  (char*)Kls + buf * 16384 + rr * 256 + kcb * 16);
    }
#pragma unroll
    for (int i = 0; i < 4; i++) {  // V^T tile: 128 x 64
      int rr = vr0 + i * 32;
      gload_lds16(Vh + (size_t)rr * 2048 + kt * 64 + ((vcb ^ (rr & 7)) * 8),
                  (char*)Vls + buf * 16384 + rr * 128 + vcb * 16);
    }
  };

  stage(0, 0);
  __syncthreads();

  const float CL2 = 0.08838834764831845f * 1.44269504088896f;  // scale * log2(e)

  for (int kt = 0; kt < 32; kt++) {
    const int cur = kt & 1;
    if (kt + 1 < 32) stage(cur ^ 1, kt + 1);  // prefetch overlaps this tile's compute

    // S^T = K @ Q^T (swapped operands): C row = k (lane>>4)*4+r, col = q (lane&15)
    f32x4 accT[4][2] = {};
#pragma unroll
    for (int kd = 0; kd < 4; kd++) {
      bf16x8 kf[4];
#pragma unroll
      for (int n = 0; n < 4; n++) {
        int row = n * 16 + (lane & 15);
        int byte = cur * 16384 + row * 256 + (((kd * 32 + (lane >> 4) * 8) * 2) ^ ((row & 7) << 4));
        kf[n] = *reinterpret_cast<const bf16x8*>((const char*)Kls + byte);
      }
      __builtin_amdgcn_s_setprio(1);
#pragma unroll
      for (int n = 0; n < 4; n++)
#pragma unroll
        for (int m = 0; m < 2; m++)
          accT[n][m] = __builtin_amdgcn_mfma_f32_16x16x32_bf16(kf[n], qf[m][kd], accT[n][m], 0, 0, 0);
      __builtin_amdgcn_s_setprio(0);
    }

    // P = exp2(S*CL2); pack 4 consecutive k as 2x cvt_pk -> one b64 LDS write
#pragma unroll
    for (int n = 0; n < 4; n++)
#pragma unroll
      for (int m = 0; m < 2; m++) {
        float p0 = fast_exp2(accT[n][m][0] * CL2);
        float p1 = fast_exp2(accT[n][m][1] * CL2);
        float p2 = fast_exp2(accT[n][m][2] * CL2);
        float p3 = fast_exp2(accT[n][m][3] * CL2);
        lsum[m] += (p0 + p1) + (p2 + p3);
        unsigned pk0, pk1;
        asm("v_cvt_pk_bf16_f32 %0, %1, %2" : "=v"(pk0) : "v"(p0), "v"(p1));
        asm("v_cvt_pk_bf16_f32 %0, %1, %2" : "=v"(pk1) : "v"(p2), "v"(p3));
        int row = w * 32 + m * 16 + (lane & 15);
        int kcol = n * 16 + (lane >> 4) * 4;
        int byte = row * 128 + ((kcol * 2) ^ ((row & 7) << 4));
        uint2 pk = {pk0, pk1};
        *reinterpret_cast<uint2*>((char*)Pls + byte) = pk;
      }

    // O += P @ V (unchanged read path)
#pragma unroll
    for (int kk = 0; kk < 2; kk++) {
      bf16x8 pf[2], vf[8];
#pragma unroll
      for (int m = 0; m < 2; m++) {
        int row = w * 32 + m * 16 + (lane & 15);
        int byte = row * 128 + (((kk * 32 + (lane >> 4) * 8) * 2) ^ ((row & 7) << 4));
        pf[m] = *reinterpret_cast<const bf16x8*>((const char*)Pls + byte);
      }
#pragma unroll
      for (int n = 0; n < 8; n++) {
        int row = n * 16 + (lane & 15);
        int byte = cur * 16384 + row * 128 + (((kk * 32 + (lane >> 4) * 8) * 2) ^ ((row & 7) << 4));
        vf[n] = *reinterpret_cast<const bf16x8*>((const char*)Vls + byte);
      }
      __builtin_amdgcn_s_setprio(1);
#pragma unroll
      for (int m = 0; m < 2; m++)
#pragma unroll
        for (int n = 0; n < 8; n++)
          accO[m][n] = __builtin_amdgcn_mfma_f32_16x16x32_bf16(pf[m], vf[n], accO[m][n], 0, 0, 0);
      __builtin_amdgcn_s_setprio(0);
    }

    __syncthreads();  // drains prefetch (vmcnt) + syncs buffer reuse
  }

  // row-sum reduce across the 4 lane-groups, redistribute 1/l to C-fragment lanes.
  const int rl = (lane >> 4) * 4;
  float rv[2][4];
#pragma unroll
  for (int m = 0; m < 2; m++) {
    float s = lsum[m];
    s += __shfl_xor(s, 16);
    s += __shfl_xor(s, 32);
    float inv = 1.0f / s;
#pragma unroll
    for (int r = 0; r < 4; r++) rv[m][r] = __shfl(inv, rl + r);
  }

  const int b = bh >> 4, h = bh & 15;
#pragma unroll
  for (int m = 0; m < 2; m++)
#pragma unroll
    for (int n = 0; n < 8; n++)
#pragma unroll
      for (int r = 0; r < 4; r++) {
        int s = q0 + w * 32 + m * 16 + rl + r;
        int d = n * 16 + (lane & 15);
        O[((size_t)(b * 2048 + s)) * 2048 + h * 128 + d] = f2bf(accO[m][n][r] * rv[m][r]);
      }
}

// ---------------- launch ----------------

extern "C" void kernel_launch(void* const* d_in, const int* in_sizes, int n_in,
                              void* d_out, int out_size, void* d_ws, size_t ws_size,
                              hipStream_t stream) {
  const float* x    = (const float*)d_in[0];
  const float* Wq   = (const float*)d_in[1];
  const float* Wdkv = (const float*)d_in[2];
  const float* Wuk  = (const float*)d_in[3];
  const float* Wuv  = (const float*)d_in[4];
  const float* Wo   = (const float*)d_in[5];

  char* ws = (char*)d_ws;
  unsigned short* xb    = (unsigned short*)(ws + 0);          // 16MB; reused as attn-out
  unsigned short* WqT   = (unsigned short*)(ws + 16777216);   // 8MB; reused as WoT
  unsigned short* WdkvT = (unsigned short*)(ws + 25165824);   // 4MB (contiguous after WqT)
  unsigned short* WukT  = (unsigned short*)(ws + 29360128);   // 2MB
  unsigned short* WuvT  = (unsigned short*)(ws + 31457280);   // 2MB
  unsigned short* dkv   = (unsigned short*)(ws + 33554432);   // 8MB
  unsigned short* q_att = (unsigned short*)(ws + 41943040);   // 16MB
  unsigned short* k_att = (unsigned short*)(ws + 58720256);   // 16MB
  unsigned short* vT    = (unsigned short*)(ws + 75497472);   // 16MB
  float* cosT           = (float*)(ws + 92274688);            // 0.5MB
  float* sinT           = (float*)(ws + 92798976);            // 0.5MB

  // fused prep: x-cvt + Wq/Wdkv/Wuk/Wuv transposes + rope table (1 dispatch)
  k_prep<<<16896, 256, 0, stream>>>(x, xb, Wq, WqT, Wdkv, WdkvT, Wuk, WukT, Wuv, WuvT, cosT, sinT);

  // merged: [q | dkv] = x @ [Wq | Wdkv]  (N=3072; q gets RoPE+scatter, dkv row-major)
  k_gemm<5><<<dim3(24, 32), 256, 0, stream>>>(xb, 2048, WqT, 2048, q_att, dkv, 4096, 3072, 2048,
                                              cosT, sinT, nullptr, nullptr, nullptr);
  // merged k|v|WoT: k=dk@Wuk+RoPE -> k_att; vT=WuvT@dv^T -> vT; Wo transpose -> WqT slot
  k_gemm<6><<<2048, 256, 0, stream>>>(dkv, 1024, WukT, 512, k_att, vT, 4096, 2048, 512,
                                      cosT, sinT, WuvT, Wo, WqT);
  // attention -> [4096][2048] bf16 (into xb slot, dead after merged GEMM)
  k_attn<<<dim3(16, 32), 256, 0, stream>>>(q_att, k_att, vT, xb);
  // out = ao @ Wo -> f32
  k_gemm<4><<<dim3(16, 32), 256, 0, stream>>>(xb, 2048, WqT, 2048, (float*)d_out, nullptr, 4096, 2048, 2048,
                                              nullptr, nullptr, nullptr, nullptr, nullptr);
}